// Round 2
// baseline (356.682 us; speedup 1.0000x reference)
//
#include <hip/hip_runtime.h>
#include <hip/hip_bf16.h>

using bf16 = __hip_bfloat16;
typedef __attribute__((ext_vector_type(8))) short bf16x8;   // 8 bf16 = 4 VGPRs (MFMA A/B frag)
typedef __attribute__((ext_vector_type(4))) float f32x4;    // MFMA C/D frag

#define DEV __device__ __forceinline__

DEV void gload_lds16(const void* g, void* l) {
  __builtin_amdgcn_global_load_lds((const __attribute__((address_space(1))) void*)g,
                                   (__attribute__((address_space(3))) void*)l, 16, 0, 0);
}

// ---------------------------------------------------------------- converts
__global__ __launch_bounds__(256) void cvt_kernel(const float* __restrict__ x,
                                                  bf16* __restrict__ y, int n8) {
  int i = blockIdx.x * 256 + threadIdx.x;
  if (i >= n8) return;
  const float4* xv = (const float4*)x;
  float4 a = xv[i * 2];
  float4 b = xv[i * 2 + 1];
  union { bf16 h[8]; uint4 v; } u;
  u.h[0] = __float2bfloat16(a.x); u.h[1] = __float2bfloat16(a.y);
  u.h[2] = __float2bfloat16(a.z); u.h[3] = __float2bfloat16(a.w);
  u.h[4] = __float2bfloat16(b.x); u.h[5] = __float2bfloat16(b.y);
  u.h[6] = __float2bfloat16(b.z); u.h[7] = __float2bfloat16(b.w);
  *(uint4*)&y[(size_t)i * 8] = u.v;
}

// W [K=1024][N=1024] f32  ->  WT [N][K] bf16
__global__ __launch_bounds__(256) void wtrans_kernel(const float* __restrict__ W,
                                                     bf16* __restrict__ WT) {
  __shared__ float tile[32][33];
  const int tx = threadIdx.x & 31, ty = threadIdx.x >> 5;  // 32 x 8
  const int n0 = blockIdx.x * 32, k0 = blockIdx.y * 32;
#pragma unroll
  for (int i = ty; i < 32; i += 8)
    tile[i][tx] = W[(size_t)(k0 + i) * 1024 + n0 + tx];
  __syncthreads();
#pragma unroll
  for (int i = ty; i < 32; i += 8)
    WT[(size_t)(n0 + i) * 1024 + k0 + tx] = __float2bfloat16(tile[tx][i]);
}

// v (projected, bf16 [4096][1024]) -> VT [bh=32][dh=64][S=2048]
__global__ __launch_bounds__(256) void vtrans_kernel(const bf16* __restrict__ v,
                                                     bf16* __restrict__ VT) {
  __shared__ bf16 tile[64 * 64];
  const int t = threadIdx.x;
  const int bh = blockIdx.y, b = bh >> 4, h = bh & 15;
  const int s0 = blockIdx.x * 64;
  const int r0 = t >> 3, c8 = t & 7;
#pragma unroll
  for (int it = 0; it < 2; ++it) {
    int r = it * 32 + r0;  // s row within tile
    uint4 d = *(const uint4*)&v[(size_t)(b * 2048 + s0 + r) * 1024 + h * 64 + c8 * 8];
    *(uint4*)&tile[r * 64 + ((c8 ^ (r >> 3)) * 8)] = d;   // swizzle on (row>>3)
  }
  __syncthreads();
#pragma unroll
  for (int it = 0; it < 2; ++it) {
    int d = it * 32 + r0;  // dh row
    int sc = c8 * 8;
    union { bf16 h[8]; uint4 v4; } u;
#pragma unroll
    for (int j = 0; j < 8; ++j) {
      int row = sc + j;
      u.h[j] = tile[row * 64 + (((d >> 3) ^ (row >> 3)) * 8) + (d & 7)];
    }
    *(uint4*)&VT[((size_t)bh * 64 + d) * 2048 + s0 + sc] = u.v4;
  }
}

// ---------------------------------------------------------------- GEMM 128x128, BK=32
template <typename OutT>
DEV void gemm128_core(const bf16* __restrict__ A, const bf16* __restrict__ BT,
                      const float* __restrict__ bias, OutT* __restrict__ out) {
  constexpr int K = 1024, N = 1024;
  __shared__ bf16 ldsA[128 * 32];
  __shared__ bf16 ldsB[128 * 32];
  const int t = threadIdx.x;
  const int lane = t & 63, wid = t >> 6;
  const int wr = wid >> 1, wc = wid & 1;
  const int fr = lane & 15, fko = (lane >> 4) * 8;
  const size_t mBase = (size_t)blockIdx.y * 128;
  const size_t nBase = (size_t)blockIdx.x * 128;

  const int srow = t >> 2;          // 0..63
  const int scol = (t & 3) * 8;     // 0/8/16/24
  const bf16* gA = A + (mBase + srow) * K + scol;
  const bf16* gB = BT + (nBase + srow) * K + scol;
  bf16* lA = ldsA + wid * 512;      // wave-uniform LDS dest (HW adds lane*16B)
  bf16* lB = ldsB + wid * 512;

  f32x4 acc[4][4];
#pragma unroll
  for (int i = 0; i < 4; ++i)
#pragma unroll
    for (int j = 0; j < 4; ++j) acc[i][j] = (f32x4){0.f, 0.f, 0.f, 0.f};

  for (int k0 = 0; k0 < K; k0 += 32) {
    gload_lds16(gA + k0, lA);
    gload_lds16(gA + 64 * K + k0, lA + 2048);
    gload_lds16(gB + k0, lB);
    gload_lds16(gB + 64 * K + k0, lB + 2048);
    asm volatile("s_waitcnt vmcnt(0)" ::: "memory");
    __syncthreads();

    bf16x8 aF[4], bF[4];
#pragma unroll
    for (int i = 0; i < 4; ++i)
      aF[i] = *(const bf16x8*)&ldsA[(wr * 64 + i * 16 + fr) * 32 + fko];
#pragma unroll
    for (int j = 0; j < 4; ++j)
      bF[j] = *(const bf16x8*)&ldsB[(wc * 64 + j * 16 + fr) * 32 + fko];
#pragma unroll
    for (int i = 0; i < 4; ++i)
#pragma unroll
      for (int j = 0; j < 4; ++j)
        acc[i][j] = __builtin_amdgcn_mfma_f32_16x16x32_bf16(aF[i], bF[j], acc[i][j], 0, 0, 0);
    __syncthreads();
  }

  const int orow = (int)mBase + wr * 64 + (lane >> 4) * 4;
  const int ocol = (int)nBase + wc * 64 + fr;
#pragma unroll
  for (int j = 0; j < 4; ++j) {
    const float bj = bias[ocol + j * 16];
#pragma unroll
    for (int i = 0; i < 4; ++i)
#pragma unroll
      for (int r = 0; r < 4; ++r) {
        float v = fmaxf(acc[i][j][r] + bj, 0.f);
        size_t idx = (size_t)(orow + i * 16 + r) * N + (ocol + j * 16);
        if constexpr (sizeof(OutT) == 2) out[idx] = __float2bfloat16(v);
        else out[idx] = v;
      }
  }
}

struct QKVArgs {
  const bf16* A[3];
  const bf16* BT[3];
  const float* bias[3];
  bf16* out[3];
};

__global__ __launch_bounds__(256) void gemm_qkv_kernel(QKVArgs args) {
  const int z = blockIdx.z;
  gemm128_core<bf16>(args.A[z], args.BT[z], args.bias[z], args.out[z]);
}

__global__ __launch_bounds__(256) void gemm_out_kernel(const bf16* __restrict__ A,
                                                       const bf16* __restrict__ BT,
                                                       const float* __restrict__ bias,
                                                       float* __restrict__ out) {
  gemm128_core<float>(A, BT, bias, out);
}

// ---------------------------------------------------------------- flash attention (causal)
// Q,K: bf16 [B*S][1024] (head h at cols h*64..), VT: bf16 [bh][64][2048]
// O: bf16 [B*S][1024]. Block: 64 q-rows (4 waves x 16), KV tiles of 64.
// Grid: (32 q-tiles, 32 bh); largest q-tile first (LPT).
__global__ __launch_bounds__(256) void attn_kernel(const bf16* __restrict__ Qb,
                                                   const bf16* __restrict__ Kb,
                                                   const bf16* __restrict__ VTb,
                                                   bf16* __restrict__ Ob) {
  constexpr int Dm = 1024, S = 2048;
  __shared__ bf16 ldsK[64 * 64];
  __shared__ bf16 ldsV[64 * 64];
  __shared__ bf16 ldsP[4 * 16 * 64];
  const int t = threadIdx.x, lane = t & 63, wid = t >> 6;
  const int bh = blockIdx.y, b = bh >> 4, h = bh & 15;
  const int qt = 31 - blockIdx.x;     // largest-first
  const int qb = qt * 64;
  const int fr = lane & 15, fg = lane >> 4;
  const int qw = qb + wid * 16;       // this wave's 16 q-rows
  const bf16* Qg = Qb + (size_t)b * S * Dm + h * 64;
  const bf16* Kg = Kb + (size_t)b * S * Dm + h * 64;
  const bf16* VTg = VTb + (size_t)bh * 64 * S;

  // Q fragments in registers (reused for all KV tiles)
  bf16x8 qF[2];
#pragma unroll
  for (int kk = 0; kk < 2; ++kk)
    qF[kk] = *(const bf16x8*)&Qg[(size_t)(qw + fr) * Dm + kk * 32 + fg * 8];

  f32x4 oacc[4];
  float mrow[4], lrow[4];
#pragma unroll
  for (int n = 0; n < 4; ++n) oacc[n] = (f32x4){0.f, 0.f, 0.f, 0.f};
#pragma unroll
  for (int r = 0; r < 4; ++r) { mrow[r] = -3.0e38f; lrow[r] = 0.f; }

  const int sr0 = t >> 3, sc8 = t & 7;
  const int nTiles = qt + 1;          // every wave is active in every tile
  bf16* pbase = ldsP + wid * 1024;

  for (int tile = 0; tile < nTiles; ++tile) {
    const int kvb = tile * 64;
    // reg-stage K tile [64 kv][64 d] and VT tile [64 d][64 kv]
    uint4 kreg[2], vreg[2];
#pragma unroll
    for (int it = 0; it < 2; ++it) {
      int r = it * 32 + sr0;
      kreg[it] = *(const uint4*)&Kg[(size_t)(kvb + r) * Dm + sc8 * 8];
      vreg[it] = *(const uint4*)&VTg[(size_t)r * S + kvb + sc8 * 8];
    }
    __syncthreads();  // previous tile's LDS reads complete before overwrite
#pragma unroll
    for (int it = 0; it < 2; ++it) {
      int r = it * 32 + sr0;
      *(uint4*)&ldsK[r * 64 + ((sc8 ^ (r & 7)) * 8)] = kreg[it];  // XOR chunk swizzle
      *(uint4*)&ldsV[r * 64 + ((sc8 ^ (r & 7)) * 8)] = vreg[it];
    }
    __syncthreads();

    // S = Q K^T — D[q=16][kv=64]
    f32x4 sf[4];
#pragma unroll
    for (int n = 0; n < 4; ++n) sf[n] = (f32x4){0.f, 0.f, 0.f, 0.f};
#pragma unroll
    for (int n = 0; n < 4; ++n) {
#pragma unroll
      for (int kk = 0; kk < 2; ++kk) {
        bf16x8 kf = *(const bf16x8*)&ldsK[(n * 16 + fr) * 64 + (((kk * 4 + fg) ^ (fr & 7)) * 8)];
        sf[n] = __builtin_amdgcn_mfma_f32_16x16x32_bf16(qF[kk], kf, sf[n], 0, 0, 0);
      }
    }
    const bool needmask = (tile == nTiles - 1);  // only the diagonal tile masks
#pragma unroll
    for (int n = 0; n < 4; ++n)
#pragma unroll
      for (int r = 0; r < 4; ++r) {
        float vv = sf[n][r] * 0.125f;  // 1/sqrt(64)
        if (needmask) {
          int kv = kvb + n * 16 + fr;
          int qr = qw + fg * 4 + r;
          if (kv > qr) vv = -1e30f;
        }
        sf[n][r] = vv;
      }
    // online softmax per row (rows live in 16-lane groups)
#pragma unroll
    for (int r = 0; r < 4; ++r) {
      float tmax = fmaxf(fmaxf(sf[0][r], sf[1][r]), fmaxf(sf[2][r], sf[3][r]));
      tmax = fmaxf(tmax, __shfl_xor(tmax, 1, 64));
      tmax = fmaxf(tmax, __shfl_xor(tmax, 2, 64));
      tmax = fmaxf(tmax, __shfl_xor(tmax, 4, 64));
      tmax = fmaxf(tmax, __shfl_xor(tmax, 8, 64));
      float mold = mrow[r];
      float mnew = fmaxf(mold, tmax);
      float corr = __expf(mold - mnew);
      mrow[r] = mnew;
      float rs = 0.f;
#pragma unroll
      for (int n = 0; n < 4; ++n) {
        float p = __expf(sf[n][r] - mnew);
        sf[n][r] = p;
        rs += p;
      }
      rs += __shfl_xor(rs, 1, 64);
      rs += __shfl_xor(rs, 2, 64);
      rs += __shfl_xor(rs, 4, 64);
      rs += __shfl_xor(rs, 8, 64);
      lrow[r] = lrow[r] * corr + rs;
#pragma unroll
      for (int n = 0; n < 4; ++n) oacc[n][r] *= corr;
    }
    // P -> LDS (bf16, swizzled, per-wave buffer) to re-shape D-layout into A-layout
#pragma unroll
    for (int n = 0; n < 4; ++n)
#pragma unroll
      for (int r = 0; r < 4; ++r) {
        int prow = fg * 4 + r;
        int col = n * 16 + fr;
        pbase[prow * 64 + (((col >> 3) ^ (prow & 7)) * 8) + (col & 7)] =
            __float2bfloat16(sf[n][r]);
      }
    asm volatile("s_waitcnt lgkmcnt(0)" ::: "memory");
    // O += P V — D[q=16][d=64]
#pragma unroll
    for (int ks = 0; ks < 2; ++ks) {
      bf16x8 pf, vf[4];
      pf = *(const bf16x8*)&pbase[fr * 64 + (((ks * 4 + fg) ^ (fr & 7)) * 8)];
#pragma unroll
      for (int n = 0; n < 4; ++n)
        vf[n] = *(const bf16x8*)&ldsV[(n * 16 + fr) * 64 + (((ks * 4 + fg) ^ (fr & 7)) * 8)];
#pragma unroll
      for (int n = 0; n < 4; ++n)
        oacc[n] = __builtin_amdgcn_mfma_f32_16x16x32_bf16(pf, vf[n], oacc[n], 0, 0, 0);
    }
  }
  // epilogue: normalize and store
#pragma unroll
  for (int r = 0; r < 4; ++r) {
    float inv = 1.f / lrow[r];
    int row = qw + fg * 4 + r;
#pragma unroll
    for (int n = 0; n < 4; ++n) {
      float vv = oacc[n][r] * inv;
      Ob[((size_t)b * S + row) * Dm + h * 64 + n * 16 + fr] = __float2bfloat16(vv);
    }
  }
}

// ---------------------------------------------------------------- launch
extern "C" void kernel_launch(void* const* d_in, const int* in_sizes, int n_in,
                              void* d_out, int out_size, void* d_ws, size_t ws_size,
                              hipStream_t stream) {
  const float* query = (const float*)d_in[0];
  const float* key   = (const float*)d_in[1];
  const float* value = (const float*)d_in[2];
  const float* Wq = (const float*)d_in[3]; const float* bq = (const float*)d_in[4];
  const float* Wk = (const float*)d_in[5]; const float* bk = (const float*)d_in[6];
  const float* Wv = (const float*)d_in[7]; const float* bv = (const float*)d_in[8];
  const float* Wo = (const float*)d_in[9]; const float* bo = (const float*)d_in[10];
  float* out = (float*)d_out;

  char* ws = (char*)d_ws;
  const size_t MB = 1024 * 1024;
  bf16* xq  = (bf16*)(ws + 0 * MB);    // 8MB — later reused as VT
  bf16* xk  = (bf16*)(ws + 8 * MB);    // 8MB — later reused as attn buffer
  bf16* xv  = (bf16*)(ws + 16 * MB);   // 8MB
  bf16* qp  = (bf16*)(ws + 24 * MB);   // 8MB
  bf16* kp  = (bf16*)(ws + 32 * MB);   // 8MB
  bf16* vp  = (bf16*)(ws + 40 * MB);   // 8MB
  bf16* WqT = (bf16*)(ws + 48 * MB);   // 2MB each
  bf16* WkT = (bf16*)(ws + 50 * MB);
  bf16* WvT = (bf16*)(ws + 52 * MB);
  bf16* WoT = (bf16*)(ws + 54 * MB);
  bf16* VT   = xq;   // safe: xq consumed by gemm_qkv before vtrans runs
  bf16* attn = xk;   // safe: xk consumed by gemm_qkv before attn runs

  const int n8 = 2 * 2048 * 1024 / 8;  // 524288
  cvt_kernel<<<2048, 256, 0, stream>>>(query, xq, n8);
  cvt_kernel<<<2048, 256, 0, stream>>>(key, xk, n8);
  cvt_kernel<<<2048, 256, 0, stream>>>(value, xv, n8);

  dim3 wg(32, 32);
  wtrans_kernel<<<wg, 256, 0, stream>>>(Wq, WqT);
  wtrans_kernel<<<wg, 256, 0, stream>>>(Wk, WkT);
  wtrans_kernel<<<wg, 256, 0, stream>>>(Wv, WvT);
  wtrans_kernel<<<wg, 256, 0, stream>>>(Wo, WoT);

  QKVArgs qa;
  qa.A[0] = xq;  qa.A[1] = xk;  qa.A[2] = xv;
  qa.BT[0] = WqT; qa.BT[1] = WkT; qa.BT[2] = WvT;
  qa.bias[0] = bq; qa.bias[1] = bk; qa.bias[2] = bv;
  qa.out[0] = qp; qa.out[1] = kp; qa.out[2] = vp;
  gemm_qkv_kernel<<<dim3(8, 32, 3), 256, 0, stream>>>(qa);

  vtrans_kernel<<<dim3(32, 32), 256, 0, stream>>>(vp, VT);
  attn_kernel<<<dim3(32, 32), 256, 0, stream>>>(qp, kp, VT, attn);
  gemm_out_kernel<<<dim3(8, 32), 256, 0, stream>>>(attn, WoT, bo, out);
}

// Round 3
// 294.630 us; speedup vs baseline: 1.2106x; 1.2106x over previous
//
#include <hip/hip_runtime.h>
#include <hip/hip_bf16.h>

using bf16 = __hip_bfloat16;
typedef __attribute__((ext_vector_type(8))) short bf16x8;   // 8 bf16 = 4 VGPRs (MFMA A/B frag)
typedef __attribute__((ext_vector_type(4))) float f32x4;    // MFMA C/D frag

#define DEV __device__ __forceinline__

DEV void gload_lds16(const void* g, void* l) {
  __builtin_amdgcn_global_load_lds((const __attribute__((address_space(1))) void*)g,
                                   (__attribute__((address_space(3))) void*)l, 16, 0, 0);
}

// ---------------------------------------------------------------- prep: 3x cvt + 4x wtrans fused
struct PrepArgs {
  const float* x[3]; bf16* y[3];      // f32 -> bf16 converts (2M elems each)
  const float* W[4]; bf16* WT[4];     // 1024x1024 transposes
};

__global__ __launch_bounds__(256) void prep_kernel(PrepArgs a) {
  __shared__ float tile[32][33];
  const int b = blockIdx.x;
  if (b < 6144) {                      // cvt: 3 tensors x 2048 blocks
    const int which = b >> 11, blk = b & 2047;
    const int i = blk * 256 + threadIdx.x;   // < 524288 always
    const float4* xv = (const float4*)a.x[which];
    float4 p = xv[i * 2];
    float4 q = xv[i * 2 + 1];
    union { bf16 h[8]; uint4 v; } u;
    u.h[0] = __float2bfloat16(p.x); u.h[1] = __float2bfloat16(p.y);
    u.h[2] = __float2bfloat16(p.z); u.h[3] = __float2bfloat16(p.w);
    u.h[4] = __float2bfloat16(q.x); u.h[5] = __float2bfloat16(q.y);
    u.h[6] = __float2bfloat16(q.z); u.h[7] = __float2bfloat16(q.w);
    *(uint4*)&a.y[which][(size_t)i * 8] = u.v;
  } else {                             // wtrans: 4 weights x 1024 blocks
    const int w = (b - 6144) >> 10, blk = (b - 6144) & 1023;
    const float* W = a.W[w];
    bf16* WT = a.WT[w];
    const int tx = threadIdx.x & 31, ty = threadIdx.x >> 5;
    const int n0 = (blk & 31) * 32, k0 = (blk >> 5) * 32;
#pragma unroll
    for (int i = ty; i < 32; i += 8)
      tile[i][tx] = W[(size_t)(k0 + i) * 1024 + n0 + tx];
    __syncthreads();
#pragma unroll
    for (int i = ty; i < 32; i += 8)
      WT[(size_t)(n0 + i) * 1024 + k0 + tx] = __float2bfloat16(tile[tx][i]);
  }
}

// v (projected, bf16 [4096][1024]) -> VT [bh=32][dh=64][S=2048]
__global__ __launch_bounds__(256) void vtrans_kernel(const bf16* __restrict__ v,
                                                     bf16* __restrict__ VT) {
  __shared__ bf16 tile[64 * 64];
  const int t = threadIdx.x;
  const int bh = blockIdx.y, b = bh >> 4, h = bh & 15;
  const int s0 = blockIdx.x * 64;
  const int r0 = t >> 3, c8 = t & 7;
#pragma unroll
  for (int it = 0; it < 2; ++it) {
    int r = it * 32 + r0;
    uint4 d = *(const uint4*)&v[(size_t)(b * 2048 + s0 + r) * 1024 + h * 64 + c8 * 8];
    *(uint4*)&tile[r * 64 + ((c8 ^ (r >> 3)) * 8)] = d;
  }
  __syncthreads();
#pragma unroll
  for (int it = 0; it < 2; ++it) {
    int d = it * 32 + r0;
    int sc = c8 * 8;
    union { bf16 h[8]; uint4 v4; } u;
#pragma unroll
    for (int j = 0; j < 8; ++j) {
      int row = sc + j;
      u.h[j] = tile[row * 64 + (((d >> 3) ^ (row >> 3)) * 8) + (d & 7)];
    }
    *(uint4*)&VT[((size_t)bh * 64 + d) * 2048 + s0 + sc] = u.v4;
  }
}

// ---------------------------------------------------------------- GEMM 128x128, BK=32
template <typename OutT>
DEV void gemm128_core(const bf16* __restrict__ A, const bf16* __restrict__ BT,
                      const float* __restrict__ bias, OutT* __restrict__ out) {
  constexpr int K = 1024, N = 1024;
  __shared__ bf16 ldsA[128 * 32];
  __shared__ bf16 ldsB[128 * 32];
  const int t = threadIdx.x;
  const int lane = t & 63, wid = t >> 6;
  const int wr = wid >> 1, wc = wid & 1;
  const int fr = lane & 15, fko = (lane >> 4) * 8;
  const size_t mBase = (size_t)blockIdx.y * 128;
  const size_t nBase = (size_t)blockIdx.x * 128;

  const int srow = t >> 2;
  const int scol = (t & 3) * 8;
  const bf16* gA = A + (mBase + srow) * K + scol;
  const bf16* gB = BT + (nBase + srow) * K + scol;
  bf16* lA = ldsA + wid * 512;
  bf16* lB = ldsB + wid * 512;

  f32x4 acc[4][4];
#pragma unroll
  for (int i = 0; i < 4; ++i)
#pragma unroll
    for (int j = 0; j < 4; ++j) acc[i][j] = (f32x4){0.f, 0.f, 0.f, 0.f};

  for (int k0 = 0; k0 < K; k0 += 32) {
    gload_lds16(gA + k0, lA);
    gload_lds16(gA + 64 * K + k0, lA + 2048);
    gload_lds16(gB + k0, lB);
    gload_lds16(gB + 64 * K + k0, lB + 2048);
    asm volatile("s_waitcnt vmcnt(0)" ::: "memory");
    __syncthreads();

    bf16x8 aF[4], bF[4];
#pragma unroll
    for (int i = 0; i < 4; ++i)
      aF[i] = *(const bf16x8*)&ldsA[(wr * 64 + i * 16 + fr) * 32 + fko];
#pragma unroll
    for (int j = 0; j < 4; ++j)
      bF[j] = *(const bf16x8*)&ldsB[(wc * 64 + j * 16 + fr) * 32 + fko];
#pragma unroll
    for (int i = 0; i < 4; ++i)
#pragma unroll
      for (int j = 0; j < 4; ++j)
        acc[i][j] = __builtin_amdgcn_mfma_f32_16x16x32_bf16(aF[i], bF[j], acc[i][j], 0, 0, 0);
    __syncthreads();
  }

  const int orow = (int)mBase + wr * 64 + (lane >> 4) * 4;
  const int ocol = (int)nBase + wc * 64 + fr;
#pragma unroll
  for (int j = 0; j < 4; ++j) {
    const float bj = bias[ocol + j * 16];
#pragma unroll
    for (int i = 0; i < 4; ++i)
#pragma unroll
      for (int r = 0; r < 4; ++r) {
        float v = fmaxf(acc[i][j][r] + bj, 0.f);
        size_t idx = (size_t)(orow + i * 16 + r) * N + (ocol + j * 16);
        if constexpr (sizeof(OutT) == 2) out[idx] = __float2bfloat16(v);
        else out[idx] = v;
      }
  }
}

struct QKVArgs {
  const bf16* A[3];
  const bf16* BT[3];
  const float* bias[3];
  bf16* out[3];
};

__global__ __launch_bounds__(256) void gemm_qkv_kernel(QKVArgs args) {
  const int z = blockIdx.z;
  gemm128_core<bf16>(args.A[z], args.BT[z], args.bias[z], args.out[z]);
}

__global__ __launch_bounds__(256) void gemm_out_kernel(const bf16* __restrict__ A,
                                                       const bf16* __restrict__ BT,
                                                       const float* __restrict__ bias,
                                                       float* __restrict__ out) {
  gemm128_core<float>(A, BT, bias, out);
}

// ---------------------------------------------------------------- flash attention (causal)
// Q,K: bf16 [B*S][1024] (head h at cols h*64..), VT: bf16 [bh][64][2048]
// Block: 64 q-rows (4 waves x 16). KV tiles of 64, double-buffered in LDS,
// staged by global_load_lds with pre-swizzled per-lane SOURCE addresses
// (LDS[R][c] = G[R][c ^ (R&7)], XOR involution so reader applies same swizzle).
// 2-phase pipeline: stage t+1 into buf^1, compute t, one barrier per tile.
__global__ __launch_bounds__(256, 4) void attn_kernel(const bf16* __restrict__ Qb,
                                                      const bf16* __restrict__ Kb,
                                                      const bf16* __restrict__ VTb,
                                                      bf16* __restrict__ Ob) {
  constexpr int Dm = 1024, S = 2048;
  __shared__ bf16 ldsK[2 * 64 * 64];
  __shared__ bf16 ldsV[2 * 64 * 64];
  __shared__ bf16 ldsP[4 * 16 * 64];
  const int t = threadIdx.x, lane = t & 63, wid = t >> 6;

  // XCD chunk swizzle: linear id -> (xcd gets 128 contiguous ids = 4 bh)
  const int lin = blockIdx.y * 32 + blockIdx.x;   // 0..1023
  const int swz = (lin & 7) * 128 + (lin >> 3);
  const int bh = swz >> 5, qt = 31 - (swz & 31);
  const int b = bh >> 4, h = bh & 15;
  const int qb = qt * 64;
  const int fr = lane & 15, fg = lane >> 4;
  const int qw = qb + wid * 16;
  const bf16* Qg = Qb + (size_t)b * S * Dm + h * 64;
  const bf16* Kg = Kb + (size_t)b * S * Dm + h * 64;
  const bf16* VTg = VTb + (size_t)bh * 64 * S;

  // per-lane pre-swizzled staging source: lane covers (row = base + l>>3, chunk = l&7)
  const int lrow = lane >> 3;
  const int lchunk = (lane & 7) ^ lrow;           // row&7 == l>>3 for our 8-row groups
  const bf16* kSrc = Kg + (size_t)(wid * 16 + lrow) * Dm + lchunk * 8;
  const bf16* vSrc = VTg + (size_t)(wid * 16 + lrow) * S + lchunk * 8;
  bf16* kDst = ldsK + wid * 16 * 64;              // wave-uniform; HW adds lane*16B
  bf16* vDst = ldsV + wid * 16 * 64;

  // Q fragments in registers (reused for all KV tiles)
  bf16x8 qF[2];
#pragma unroll
  for (int kk = 0; kk < 2; ++kk)
    qF[kk] = *(const bf16x8*)&Qg[(size_t)(qw + fr) * Dm + kk * 32 + fg * 8];

  f32x4 oacc[4];
  float mrow[4], lrow_[4];
#pragma unroll
  for (int n = 0; n < 4; ++n) oacc[n] = (f32x4){0.f, 0.f, 0.f, 0.f};
#pragma unroll
  for (int r = 0; r < 4; ++r) { mrow[r] = -3.0e38f; lrow_[r] = 0.f; }

  const int nTiles = qt + 1;
  bf16* pbase = ldsP + wid * 1024;

  // prologue: stage tile 0 into buf 0
  {
    gload_lds16(kSrc, kDst);
    gload_lds16(kSrc + 8 * Dm, kDst + 8 * 64);
    gload_lds16(vSrc, vDst);
    gload_lds16(vSrc + 8 * S, vDst + 8 * 64);
  }
  __syncthreads();   // drains vmcnt + lgkm before barrier

  int buf = 0;
  for (int tile = 0; tile < nTiles; ++tile) {
    const int kvb = tile * 64;
    // stage next tile into the other buffer (loads fly during compute)
    if (tile + 1 < nTiles) {
      const int nb = kvb + 64;
      bf16* kD = kDst + (buf ^ 1) * 4096;
      bf16* vD = vDst + (buf ^ 1) * 4096;
      const bf16* kS = kSrc + (size_t)nb * Dm;
      const bf16* vS = vSrc + nb;
      gload_lds16(kS, kD);
      gload_lds16(kS + 8 * Dm, kD + 8 * 64);
      gload_lds16(vS, vD);
      gload_lds16(vS + 8 * S, vD + 8 * 64);
    }
    const int bo = buf * 4096;

    // S = Q K^T — D[q=16][kv=64]
    f32x4 sf[4];
#pragma unroll
    for (int n = 0; n < 4; ++n) sf[n] = (f32x4){0.f, 0.f, 0.f, 0.f};
#pragma unroll
    for (int n = 0; n < 4; ++n) {
#pragma unroll
      for (int kk = 0; kk < 2; ++kk) {
        bf16x8 kf = *(const bf16x8*)&ldsK[bo + (n * 16 + fr) * 64 + (((kk * 4 + fg) ^ (fr & 7)) * 8)];
        sf[n] = __builtin_amdgcn_mfma_f32_16x16x32_bf16(qF[kk], kf, sf[n], 0, 0, 0);
      }
    }
    const bool needmask = (tile == nTiles - 1);
#pragma unroll
    for (int n = 0; n < 4; ++n)
#pragma unroll
      for (int r = 0; r < 4; ++r) {
        float vv = sf[n][r] * 0.125f;  // 1/sqrt(64)
        if (needmask) {
          int kv = kvb + n * 16 + fr;
          int qr = qw + fg * 4 + r;
          if (kv > qr) vv = -1e30f;
        }
        sf[n][r] = vv;
      }
    // online softmax per row (rows live in 16-lane groups)
#pragma unroll
    for (int r = 0; r < 4; ++r) {
      float tmax = fmaxf(fmaxf(sf[0][r], sf[1][r]), fmaxf(sf[2][r], sf[3][r]));
      tmax = fmaxf(tmax, __shfl_xor(tmax, 1, 64));
      tmax = fmaxf(tmax, __shfl_xor(tmax, 2, 64));
      tmax = fmaxf(tmax, __shfl_xor(tmax, 4, 64));
      tmax = fmaxf(tmax, __shfl_xor(tmax, 8, 64));
      float mold = mrow[r];
      float mnew = fmaxf(mold, tmax);
      float corr = __expf(mold - mnew);
      mrow[r] = mnew;
      float rs = 0.f;
#pragma unroll
      for (int n = 0; n < 4; ++n) {
        float p = __expf(sf[n][r] - mnew);
        sf[n][r] = p;
        rs += p;
      }
      rs += __shfl_xor(rs, 1, 64);
      rs += __shfl_xor(rs, 2, 64);
      rs += __shfl_xor(rs, 4, 64);
      rs += __shfl_xor(rs, 8, 64);
      lrow_[r] = lrow_[r] * corr + rs;
#pragma unroll
      for (int n = 0; n < 4; ++n) oacc[n][r] *= corr;
    }
    // P -> LDS (bf16, swizzled, per-wave buffer)
#pragma unroll
    for (int n = 0; n < 4; ++n)
#pragma unroll
      for (int r = 0; r < 4; ++r) {
        int prow = fg * 4 + r;
        int col = n * 16 + fr;
        pbase[prow * 64 + (((col >> 3) ^ (prow & 7)) * 8) + (col & 7)] =
            __float2bfloat16(sf[n][r]);
      }
    asm volatile("s_waitcnt lgkmcnt(0)" ::: "memory");
    // O += P V — D[q=16][d=64]
#pragma unroll
    for (int ks = 0; ks < 2; ++ks) {
      bf16x8 pf, vf[4];
      pf = *(const bf16x8*)&pbase[fr * 64 + (((ks * 4 + fg) ^ (fr & 7)) * 8)];
#pragma unroll
      for (int n = 0; n < 4; ++n)
        vf[n] = *(const bf16x8*)&ldsV[bo + (n * 16 + fr) * 64 + (((ks * 4 + fg) ^ (fr & 7)) * 8)];
#pragma unroll
      for (int n = 0; n < 4; ++n)
        oacc[n] = __builtin_amdgcn_mfma_f32_16x16x32_bf16(pf, vf[n], oacc[n], 0, 0, 0);
    }
    __syncthreads();   // built-in vmcnt(0) drain lands the prefetch; guards buf overwrite
    buf ^= 1;
  }
  // epilogue: normalize and store
#pragma unroll
  for (int r = 0; r < 4; ++r) {
    float inv = 1.f / lrow_[r];
    int row = qw + fg * 4 + r;
#pragma unroll
    for (int n = 0; n < 4; ++n) {
      float vv = oacc[n][r] * inv;
      Ob[((size_t)b * S + row) * Dm + h * 64 + n * 16 + fr] = __float2bfloat16(vv);
    }
  }
}

// ---------------------------------------------------------------- launch
extern "C" void kernel_launch(void* const* d_in, const int* in_sizes, int n_in,
                              void* d_out, int out_size, void* d_ws, size_t ws_size,
                              hipStream_t stream) {
  const float* query = (const float*)d_in[0];
  const float* key   = (const float*)d_in[1];
  const float* value = (const float*)d_in[2];
  const float* Wq = (const float*)d_in[3]; const float* bq = (const float*)d_in[4];
  const float* Wk = (const float*)d_in[5]; const float* bk = (const float*)d_in[6];
  const float* Wv = (const float*)d_in[7]; const float* bv = (const float*)d_in[8];
  const float* Wo = (const float*)d_in[9]; const float* bo = (const float*)d_in[10];
  float* out = (float*)d_out;

  char* ws = (char*)d_ws;
  const size_t MB = 1024 * 1024;
  bf16* xq  = (bf16*)(ws + 0 * MB);    // 8MB — later reused as VT
  bf16* xk  = (bf16*)(ws + 8 * MB);    // 8MB — later reused as attn buffer
  bf16* xv  = (bf16*)(ws + 16 * MB);   // 8MB
  bf16* qp  = (bf16*)(ws + 24 * MB);   // 8MB
  bf16* kp  = (bf16*)(ws + 32 * MB);   // 8MB
  bf16* vp  = (bf16*)(ws + 40 * MB);   // 8MB
  bf16* WqT = (bf16*)(ws + 48 * MB);   // 2MB each
  bf16* WkT = (bf16*)(ws + 50 * MB);
  bf16* WvT = (bf16*)(ws + 52 * MB);
  bf16* WoT = (bf16*)(ws + 54 * MB);
  bf16* VT   = xq;   // safe: xq consumed by gemm_qkv before vtrans runs
  bf16* attn = xk;   // safe: xk consumed by gemm_qkv before attn runs

  PrepArgs pa;
  pa.x[0] = query; pa.x[1] = key; pa.x[2] = value;
  pa.y[0] = xq; pa.y[1] = xk; pa.y[2] = xv;
  pa.W[0] = Wq; pa.W[1] = Wk; pa.W[2] = Wv; pa.W[3] = Wo;
  pa.WT[0] = WqT; pa.WT[1] = WkT; pa.WT[2] = WvT; pa.WT[3] = WoT;
  prep_kernel<<<10240, 256, 0, stream>>>(pa);

  QKVArgs qa;
  qa.A[0] = xq;  qa.A[1] = xk;  qa.A[2] = xv;
  qa.BT[0] = WqT; qa.BT[1] = WkT; qa.BT[2] = WvT;
  qa.bias[0] = bq; qa.bias[1] = bk; qa.bias[2] = bv;
  qa.out[0] = qp; qa.out[1] = kp; qa.out[2] = vp;
  gemm_qkv_kernel<<<dim3(8, 32, 3), 256, 0, stream>>>(qa);

  vtrans_kernel<<<dim3(32, 32), 256, 0, stream>>>(vp, VT);
  attn_kernel<<<dim3(32, 32), 256, 0, stream>>>(qp, kp, VT, attn);
  gemm_out_kernel<<<dim3(8, 32), 256, 0, stream>>>(attn, WoT, bo, out);
}

// Round 4
// 270.194 us; speedup vs baseline: 1.3201x; 1.0904x over previous
//
#include <hip/hip_runtime.h>
#include <hip/hip_bf16.h>

using bf16 = __hip_bfloat16;
typedef __attribute__((ext_vector_type(8))) short bf16x8;   // 8 bf16 = 4 VGPRs (MFMA A/B frag)
typedef __attribute__((ext_vector_type(4))) float f32x4;    // MFMA C/D frag

#define DEV __device__ __forceinline__

DEV void gload_lds16(const void* g, void* l) {
  __builtin_amdgcn_global_load_lds((const __attribute__((address_space(1))) void*)g,
                                   (__attribute__((address_space(3))) void*)l, 16, 0, 0);
}

DEV unsigned pk2(float lo, float hi) {   // pack 2 f32 -> 2 bf16 (compiler emits cvt_pk)
  union { bf16 h[2]; unsigned u; } z;
  z.h[0] = __float2bfloat16(lo);
  z.h[1] = __float2bfloat16(hi);
  return z.u;
}

// ---------------------------------------------------------------- prep: 3x cvt + 4x wtrans fused
struct PrepArgs {
  const float* x[3]; bf16* y[3];
  const float* W[4]; bf16* WT[4];
};

__global__ __launch_bounds__(256) void prep_kernel(PrepArgs a) {
  __shared__ float tile[32][33];
  const int b = blockIdx.x;
  if (b < 6144) {
    const int which = b >> 11, blk = b & 2047;
    const int i = blk * 256 + threadIdx.x;
    const float4* xv = (const float4*)a.x[which];
    float4 p = xv[i * 2];
    float4 q = xv[i * 2 + 1];
    union { bf16 h[8]; uint4 v; } u;
    u.h[0] = __float2bfloat16(p.x); u.h[1] = __float2bfloat16(p.y);
    u.h[2] = __float2bfloat16(p.z); u.h[3] = __float2bfloat16(p.w);
    u.h[4] = __float2bfloat16(q.x); u.h[5] = __float2bfloat16(q.y);
    u.h[6] = __float2bfloat16(q.z); u.h[7] = __float2bfloat16(q.w);
    *(uint4*)&a.y[which][(size_t)i * 8] = u.v;
  } else {
    const int w = (b - 6144) >> 10, blk = (b - 6144) & 1023;
    const float* W = a.W[w];
    bf16* WT = a.WT[w];
    const int tx = threadIdx.x & 31, ty = threadIdx.x >> 5;
    const int n0 = (blk & 31) * 32, k0 = (blk >> 5) * 32;
#pragma unroll
    for (int i = ty; i < 32; i += 8)
      tile[i][tx] = W[(size_t)(k0 + i) * 1024 + n0 + tx];
    __syncthreads();
#pragma unroll
    for (int i = ty; i < 32; i += 8)
      WT[(size_t)(n0 + i) * 1024 + k0 + tx] = __float2bfloat16(tile[tx][i]);
  }
}

// v (projected, bf16 [4096][1024]) -> VT [bh=32][dh=64][S=2048]
__global__ __launch_bounds__(256) void vtrans_kernel(const bf16* __restrict__ v,
                                                     bf16* __restrict__ VT) {
  __shared__ bf16 tile[64 * 64];
  const int t = threadIdx.x;
  const int bh = blockIdx.y, b = bh >> 4, h = bh & 15;
  const int s0 = blockIdx.x * 64;
  const int r0 = t >> 3, c8 = t & 7;
#pragma unroll
  for (int it = 0; it < 2; ++it) {
    int r = it * 32 + r0;
    uint4 d = *(const uint4*)&v[(size_t)(b * 2048 + s0 + r) * 1024 + h * 64 + c8 * 8];
    *(uint4*)&tile[r * 64 + ((c8 ^ (r >> 3)) * 8)] = d;
  }
  __syncthreads();
#pragma unroll
  for (int it = 0; it < 2; ++it) {
    int d = it * 32 + r0;
    int sc = c8 * 8;
    union { bf16 h[8]; uint4 v4; } u;
#pragma unroll
    for (int j = 0; j < 8; ++j) {
      int row = sc + j;
      u.h[j] = tile[row * 64 + (((d >> 3) ^ (row >> 3)) * 8) + (d & 7)];
    }
    *(uint4*)&VT[((size_t)bh * 64 + d) * 2048 + s0 + sc] = u.v4;
  }
}

// ---------------------------------------------------------------- GEMM 128x128, BK=32 (unchanged)
template <typename OutT>
DEV void gemm128_core(const bf16* __restrict__ A, const bf16* __restrict__ BT,
                      const float* __restrict__ bias, OutT* __restrict__ out) {
  constexpr int K = 1024, N = 1024;
  __shared__ bf16 ldsA[128 * 32];
  __shared__ bf16 ldsB[128 * 32];
  const int t = threadIdx.x;
  const int lane = t & 63, wid = t >> 6;
  const int wr = wid >> 1, wc = wid & 1;
  const int fr = lane & 15, fko = (lane >> 4) * 8;
  const size_t mBase = (size_t)blockIdx.y * 128;
  const size_t nBase = (size_t)blockIdx.x * 128;

  const int srow = t >> 2;
  const int scol = (t & 3) * 8;
  const bf16* gA = A + (mBase + srow) * K + scol;
  const bf16* gB = BT + (nBase + srow) * K + scol;
  bf16* lA = ldsA + wid * 512;
  bf16* lB = ldsB + wid * 512;

  f32x4 acc[4][4];
#pragma unroll
  for (int i = 0; i < 4; ++i)
#pragma unroll
    for (int j = 0; j < 4; ++j) acc[i][j] = (f32x4){0.f, 0.f, 0.f, 0.f};

  for (int k0 = 0; k0 < K; k0 += 32) {
    gload_lds16(gA + k0, lA);
    gload_lds16(gA + 64 * K + k0, lA + 2048);
    gload_lds16(gB + k0, lB);
    gload_lds16(gB + 64 * K + k0, lB + 2048);
    asm volatile("s_waitcnt vmcnt(0)" ::: "memory");
    __syncthreads();

    bf16x8 aF[4], bF[4];
#pragma unroll
    for (int i = 0; i < 4; ++i)
      aF[i] = *(const bf16x8*)&ldsA[(wr * 64 + i * 16 + fr) * 32 + fko];
#pragma unroll
    for (int j = 0; j < 4; ++j)
      bF[j] = *(const bf16x8*)&ldsB[(wc * 64 + j * 16 + fr) * 32 + fko];
#pragma unroll
    for (int i = 0; i < 4; ++i)
#pragma unroll
      for (int j = 0; j < 4; ++j)
        acc[i][j] = __builtin_amdgcn_mfma_f32_16x16x32_bf16(aF[i], bF[j], acc[i][j], 0, 0, 0);
    __syncthreads();
  }

  const int orow = (int)mBase + wr * 64 + (lane >> 4) * 4;
  const int ocol = (int)nBase + wc * 64 + fr;
#pragma unroll
  for (int j = 0; j < 4; ++j) {
    const float bj = bias[ocol + j * 16];
#pragma unroll
    for (int i = 0; i < 4; ++i)
#pragma unroll
      for (int r = 0; r < 4; ++r) {
        float v = fmaxf(acc[i][j][r] + bj, 0.f);
        size_t idx = (size_t)(orow + i * 16 + r) * N + (ocol + j * 16);
        if constexpr (sizeof(OutT) == 2) out[idx] = __float2bfloat16(v);
        else out[idx] = v;
      }
  }
}

struct QKVArgs {
  const bf16* A[3];
  const bf16* BT[3];
  const float* bias[3];
  bf16* out[3];
};

__global__ __launch_bounds__(256) void gemm_qkv_kernel(QKVArgs args) {
  const int z = blockIdx.z;
  gemm128_core<bf16>(args.A[z], args.BT[z], args.bias[z], args.out[z]);
}

__global__ __launch_bounds__(256) void gemm_out_kernel(const bf16* __restrict__ A,
                                                       const bf16* __restrict__ BT,
                                                       const float* __restrict__ bias,
                                                       float* __restrict__ out) {
  gemm128_core<float>(A, BT, bias, out);
}

// ---------------------------------------------------------------- flash attention (causal, swapped QK^T)
// Q,K: bf16 [B*S][1024] (head h at cols h*64..), VT: bf16 [bh][64][2048]
// Block: 64 q-rows (4 waves x 16 rows). KV tiles of 64, double-buffered LDS via
// global_load_lds with pre-swizzled source. QK^T computed SWAPPED: S^T = mfma(K, Q)
// so D col = q -> each lane owns one q-row's P values; softmax = in-lane tree +
// 2 shfl_xor. PV: O^T = mfma(V^T, P^T) with P^T B-frag built in-register via
// cvt_pk + ds_bpermute (no LDS P). Epilogue: per-wave LDS transpose of O^T.
__global__ __launch_bounds__(256, 4) void attn_kernel(const bf16* __restrict__ Qb,
                                                      const bf16* __restrict__ Kb,
                                                      const bf16* __restrict__ VTb,
                                                      bf16* __restrict__ Ob) {
  constexpr int Dm = 1024, S = 2048;
  __shared__ bf16 ldsKV[16384];   // [K buf0|K buf1|V buf0|V buf1] 4096 each (32KB)
  const int t = threadIdx.x, l = t & 63, wid = t >> 6;

  // XCD chunk swizzle (bijective, 1024 = 8*128)
  const int lin = blockIdx.y * 32 + blockIdx.x;
  const int swz = (lin & 7) * 128 + (lin >> 3);
  const int bh = swz >> 5, qt = 31 - (swz & 31);   // LPT within each XCD run
  const int b = bh >> 4, h = bh & 15;
  const int qb = qt * 64;
  const int q4 = l & 15, fg = l >> 4;              // lane's q-col, k-group
  const int qw = qb + wid * 16;                    // this wave's 16 q-rows
  const bf16* Qg = Qb + (size_t)b * S * Dm + h * 64;
  const bf16* Kg = Kb + (size_t)b * S * Dm + h * 64;
  const bf16* VTg = VTb + (size_t)bh * 64 * S;

  // staging: lane covers (row = base + l>>3 (+8), chunk = (l&7) ^ (row&7))
  const int srow = l >> 3;
  const int schunk = (l & 7) ^ srow;
  const bf16* kSrc = Kg + (size_t)(wid * 16 + srow) * Dm + schunk * 8;
  const bf16* vSrc = VTg + (size_t)(wid * 16 + srow) * S + schunk * 8;
  bf16* kDst = ldsKV + wid * 1024;                 // + buf*4096
  bf16* vDst = ldsKV + 8192 + wid * 1024;

  // Q fragments (B-operand: col=q4, k-elems fg*8.. of d-slice kd*32)
  bf16x8 qF[2];
#pragma unroll
  for (int kd = 0; kd < 2; ++kd)
    qF[kd] = *(const bf16x8*)&Qg[(size_t)(qw + q4) * Dm + kd * 32 + fg * 8];

  f32x4 oacc[4];                                   // O^T: [d-block][q] accum
#pragma unroll
  for (int n = 0; n < 4; ++n) oacc[n] = (f32x4){0.f, 0.f, 0.f, 0.f};
  float mrow = -3.0e38f, lsum = 0.f;               // per-lane scalars (one q-row)

  // bpermute indices for P^T B-frag build
  const int idx0 = ((q4 + ((l & 16) ? 32 : 0)) << 2);
  const int idx1 = idx0 + 64;

  const int nTiles = qt + 1;

  // prologue: stage tile 0 into buf 0
  gload_lds16(kSrc, kDst);
  gload_lds16(kSrc + 8 * Dm, kDst + 512);
  gload_lds16(vSrc, vDst);
  gload_lds16(vSrc + 8 * S, vDst + 512);
  __syncthreads();

  int buf = 0;
  for (int tile = 0; tile < nTiles; ++tile) {
    const int kvb = tile * 64;
    if (tile + 1 < nTiles) {                       // prefetch next tile
      const int nb = kvb + 64;
      gload_lds16(kSrc + (size_t)nb * Dm, kDst + (buf ^ 1) * 4096);
      gload_lds16(kSrc + (size_t)(nb + 8) * Dm, kDst + (buf ^ 1) * 4096 + 512);
      gload_lds16(vSrc + nb, vDst + (buf ^ 1) * 4096);
      gload_lds16(vSrc + nb + 8 * S, vDst + (buf ^ 1) * 4096 + 512);
    }
    const bf16* kb = ldsKV + buf * 4096;
    const bf16* vb = ldsKV + 8192 + buf * 4096;

    // S^T = K Q^T : D[kv][q], col = q4
    f32x4 sT[4];
#pragma unroll
    for (int n = 0; n < 4; ++n) sT[n] = (f32x4){0.f, 0.f, 0.f, 0.f};
#pragma unroll
    for (int n = 0; n < 4; ++n) {
#pragma unroll
      for (int kd = 0; kd < 2; ++kd) {
        bf16x8 kf = *(const bf16x8*)&kb[(n * 16 + q4) * 64 + (((kd * 4 + fg) ^ (q4 & 7)) * 8)];
        sT[n] = __builtin_amdgcn_mfma_f32_16x16x32_bf16(kf, qF[kd], sT[n], 0, 0, 0);
      }
    }
    // scale + causal mask (only diagonal tile masks)
    const bool needmask = (tile == nTiles - 1);
    const int qrow = qw + q4;
#pragma unroll
    for (int n = 0; n < 4; ++n)
#pragma unroll
      for (int r = 0; r < 4; ++r) {
        float vv = sT[n][r] * 0.125f;              // 1/sqrt(64)
        if (needmask) {
          int kv = kvb + n * 16 + fg * 4 + r;
          if (kv > qrow) vv = -1e30f;
        }
        sT[n][r] = vv;
      }
    // online softmax: in-lane tree over 16 + 2 shfl_xor across k-groups
    float tmax = -3.0e38f;
#pragma unroll
    for (int n = 0; n < 4; ++n)
      tmax = fmaxf(tmax, fmaxf(fmaxf(sT[n][0], sT[n][1]), fmaxf(sT[n][2], sT[n][3])));
    tmax = fmaxf(tmax, __shfl_xor(tmax, 16, 64));
    tmax = fmaxf(tmax, __shfl_xor(tmax, 32, 64));
    const float mnew = fmaxf(mrow, tmax);
    const float corr = __expf(mrow - mnew);
    mrow = mnew;
    float rs = 0.f;
#pragma unroll
    for (int n = 0; n < 4; ++n)
#pragma unroll
      for (int r = 0; r < 4; ++r) {
        float p = __expf(sT[n][r] - mnew);
        sT[n][r] = p;
        rs += p;
      }
    rs += __shfl_xor(rs, 16, 64);
    rs += __shfl_xor(rs, 32, 64);
    lsum = lsum * corr + rs;
#pragma unroll
    for (int n = 0; n < 4; ++n)
#pragma unroll
      for (int r = 0; r < 4; ++r) oacc[n][r] *= corr;

    // PV: O^T += V^T P^T. Build P^T B-frags in-register.
#pragma unroll
    for (int ks = 0; ks < 2; ++ks) {
      const unsigned X0 = pk2(sT[2 * ks][0], sT[2 * ks][1]);
      const unsigned X1 = pk2(sT[2 * ks][2], sT[2 * ks][3]);
      const unsigned Y0 = pk2(sT[2 * ks + 1][0], sT[2 * ks + 1][1]);
      const unsigned Y1 = pk2(sT[2 * ks + 1][2], sT[2 * ks + 1][3]);
      union { int u[4]; bf16x8 v; } bfr;
      {
        int zx = __builtin_amdgcn_ds_bpermute(idx0, (int)X0);
        int zy = __builtin_amdgcn_ds_bpermute(idx0, (int)Y0);
        bfr.u[0] = (l & 32) ? zy : zx;
        zx = __builtin_amdgcn_ds_bpermute(idx0, (int)X1);
        zy = __builtin_amdgcn_ds_bpermute(idx0, (int)Y1);
        bfr.u[1] = (l & 32) ? zy : zx;
        zx = __builtin_amdgcn_ds_bpermute(idx1, (int)X0);
        zy = __builtin_amdgcn_ds_bpermute(idx1, (int)Y0);
        bfr.u[2] = (l & 32) ? zy : zx;
        zx = __builtin_amdgcn_ds_bpermute(idx1, (int)X1);
        zy = __builtin_amdgcn_ds_bpermute(idx1, (int)Y1);
        bfr.u[3] = (l & 32) ? zy : zx;
      }
#pragma unroll
      for (int dblk = 0; dblk < 4; ++dblk) {
        bf16x8 vf = *(const bf16x8*)&vb[(dblk * 16 + q4) * 64 + (((ks * 4 + fg) ^ (q4 & 7)) * 8)];
        oacc[dblk] = __builtin_amdgcn_mfma_f32_16x16x32_bf16(vf, bfr.v, oacc[dblk], 0, 0, 0);
      }
    }
    __syncthreads();   // drains prefetch (vmcnt0) + guards buf overwrite
    buf ^= 1;
  }

  // epilogue: per-wave LDS transpose of O^T -> coalesced store
  bf16* ldsT = ldsKV + wid * 1152;                 // 16 rows x 72 (pad) bf16
  const float inv = 1.f / lsum;
#pragma unroll
  for (int dblk = 0; dblk < 4; ++dblk)
#pragma unroll
    for (int r = 0; r < 4; ++r) {
      int d = dblk * 16 + fg * 4 + r;
      ldsT[q4 * 72 + d] = __float2bfloat16(oacc[dblk][r] * inv);
    }
  asm volatile("s_waitcnt lgkmcnt(0)" ::: "memory");
  __builtin_amdgcn_sched_barrier(0);
  const int rq = l >> 2, dq = (l & 3) * 16;
#pragma unroll
  for (int i = 0; i < 2; ++i) {
    uint4 w = *(const uint4*)&ldsT[rq * 72 + dq + 8 * i];
    *(uint4*)&Ob[((size_t)b * S + qw + rq) * Dm + h * 64 + dq + 8 * i] = w;
  }
}

// ---------------------------------------------------------------- launch
extern "C" void kernel_launch(void* const* d_in, const int* in_sizes, int n_in,
                              void* d_out, int out_size, void* d_ws, size_t ws_size,
                              hipStream_t stream) {
  const float* query = (const float*)d_in[0];
  const float* key   = (const float*)d_in[1];
  const float* value = (const float*)d_in[2];
  const float* Wq = (const float*)d_in[3]; const float* bq = (const float*)d_in[4];
  const float* Wk = (const float*)d_in[5]; const float* bk = (const float*)d_in[6];
  const float* Wv = (const float*)d_in[7]; const float* bv = (const float*)d_in[8];
  const float* Wo = (const float*)d_in[9]; const float* bo = (const float*)d_in[10];
  float* out = (float*)d_out;

  char* ws = (char*)d_ws;
  const size_t MB = 1024 * 1024;
  bf16* xq  = (bf16*)(ws + 0 * MB);
  bf16* xk  = (bf16*)(ws + 8 * MB);
  bf16* xv  = (bf16*)(ws + 16 * MB);
  bf16* qp  = (bf16*)(ws + 24 * MB);
  bf16* kp  = (bf16*)(ws + 32 * MB);
  bf16* vp  = (bf16*)(ws + 40 * MB);
  bf16* WqT = (bf16*)(ws + 48 * MB);
  bf16* WkT = (bf16*)(ws + 50 * MB);
  bf16* WvT = (bf16*)(ws + 52 * MB);
  bf16* WoT = (bf16*)(ws + 54 * MB);
  bf16* VT   = xq;   // xq consumed by gemm_qkv before vtrans runs
  bf16* attn = xk;   // xk consumed by gemm_qkv before attn runs

  PrepArgs pa;
  pa.x[0] = query; pa.x[1] = key; pa.x[2] = value;
  pa.y[0] = xq; pa.y[1] = xk; pa.y[2] = xv;
  pa.W[0] = Wq; pa.W[1] = Wk; pa.W[2] = Wv; pa.W[3] = Wo;
  pa.WT[0] = WqT; pa.WT[1] = WkT; pa.WT[2] = WvT; pa.WT[3] = WoT;
  prep_kernel<<<10240, 256, 0, stream>>>(pa);

  QKVArgs qa;
  qa.A[0] = xq;  qa.A[1] = xk;  qa.A[2] = xv;
  qa.BT[0] = WqT; qa.BT[1] = WkT; qa.BT[2] = WvT;
  qa.bias[0] = bq; qa.bias[1] = bk; qa.bias[2] = bv;
  qa.out[0] = qp; qa.out[1] = kp; qa.out[2] = vp;
  gemm_qkv_kernel<<<dim3(8, 32, 3), 256, 0, stream>>>(qa);

  vtrans_kernel<<<dim3(32, 32), 256, 0, stream>>>(vp, VT);
  attn_kernel<<<dim3(32, 32), 256, 0, stream>>>(qp, kp, VT, attn);
  gemm_out_kernel<<<dim3(8, 32), 256, 0, stream>>>(attn, WoT, bo, out);
}

// Round 5
// 238.952 us; speedup vs baseline: 1.4927x; 1.1307x over previous
//
#include <hip/hip_runtime.h>
#include <hip/hip_bf16.h>

using bf16 = __hip_bfloat16;
typedef __attribute__((ext_vector_type(8))) short bf16x8;   // 8 bf16 = 4 VGPRs (MFMA A/B frag)
typedef __attribute__((ext_vector_type(4))) float f32x4;    // MFMA C/D frag

#define DEV __device__ __forceinline__

DEV void gload_lds16(const void* g, void* l) {
  __builtin_amdgcn_global_load_lds((const __attribute__((address_space(1))) void*)g,
                                   (__attribute__((address_space(3))) void*)l, 16, 0, 0);
}

DEV unsigned pk2(float lo, float hi) {   // pack 2 f32 -> 2 bf16
  union { bf16 h[2]; unsigned u; } z;
  z.h[0] = __float2bfloat16(lo);
  z.h[1] = __float2bfloat16(hi);
  return z.u;
}

// ---------------------------------------------------------------- prep: 3x cvt + 4x wtrans fused
struct PrepArgs {
  const float* x[3]; bf16* y[3];
  const float* W[4]; bf16* WT[4];
};

__global__ __launch_bounds__(256) void prep_kernel(PrepArgs a) {
  __shared__ float tile[32][33];
  const int b = blockIdx.x;
  if (b < 6144) {
    const int which = b >> 11, blk = b & 2047;
    const int i = blk * 256 + threadIdx.x;
    const float4* xv = (const float4*)a.x[which];
    float4 p = xv[i * 2];
    float4 q = xv[i * 2 + 1];
    union { bf16 h[8]; uint4 v; } u;
    u.h[0] = __float2bfloat16(p.x); u.h[1] = __float2bfloat16(p.y);
    u.h[2] = __float2bfloat16(p.z); u.h[3] = __float2bfloat16(p.w);
    u.h[4] = __float2bfloat16(q.x); u.h[5] = __float2bfloat16(q.y);
    u.h[6] = __float2bfloat16(q.z); u.h[7] = __float2bfloat16(q.w);
    *(uint4*)&a.y[which][(size_t)i * 8] = u.v;
  } else {
    const int w = (b - 6144) >> 10, blk = (b - 6144) & 1023;
    const float* W = a.W[w];
    bf16* WT = a.WT[w];
    const int tx = threadIdx.x & 31, ty = threadIdx.x >> 5;
    const int n0 = (blk & 31) * 32, k0 = (blk >> 5) * 32;
#pragma unroll
    for (int i = ty; i < 32; i += 8)
      tile[i][tx] = W[(size_t)(k0 + i) * 1024 + n0 + tx];
    __syncthreads();
#pragma unroll
    for (int i = ty; i < 32; i += 8)
      WT[(size_t)(n0 + i) * 1024 + k0 + tx] = __float2bfloat16(tile[tx][i]);
  }
}

// v (projected, bf16 [4096][1024]) -> VT [bh=32][dh=64][S=2048]
__global__ __launch_bounds__(256) void vtrans_kernel(const bf16* __restrict__ v,
                                                     bf16* __restrict__ VT) {
  __shared__ bf16 tile[64 * 64];
  const int t = threadIdx.x;
  const int bh = blockIdx.y, b = bh >> 4, h = bh & 15;
  const int s0 = blockIdx.x * 64;
  const int r0 = t >> 3, c8 = t & 7;
#pragma unroll
  for (int it = 0; it < 2; ++it) {
    int r = it * 32 + r0;
    uint4 d = *(const uint4*)&v[(size_t)(b * 2048 + s0 + r) * 1024 + h * 64 + c8 * 8];
    *(uint4*)&tile[r * 64 + ((c8 ^ (r >> 3)) * 8)] = d;
  }
  __syncthreads();
#pragma unroll
  for (int it = 0; it < 2; ++it) {
    int d = it * 32 + r0;
    int sc = c8 * 8;
    union { bf16 h[8]; uint4 v4; } u;
#pragma unroll
    for (int j = 0; j < 8; ++j) {
      int row = sc + j;
      u.h[j] = tile[row * 64 + (((d >> 3) ^ (row >> 3)) * 8) + (d & 7)];
    }
    *(uint4*)&VT[((size_t)bh * 64 + d) * 2048 + s0 + sc] = u.v4;
  }
}

// ---------------------------------------------------------------- GEMM 128x128, BK=32 (unchanged)
template <typename OutT>
DEV void gemm128_core(const bf16* __restrict__ A, const bf16* __restrict__ BT,
                      const float* __restrict__ bias, OutT* __restrict__ out) {
  constexpr int K = 1024, N = 1024;
  __shared__ bf16 ldsA[128 * 32];
  __shared__ bf16 ldsB[128 * 32];
  const int t = threadIdx.x;
  const int lane = t & 63, wid = t >> 6;
  const int wr = wid >> 1, wc = wid & 1;
  const int fr = lane & 15, fko = (lane >> 4) * 8;
  const size_t mBase = (size_t)blockIdx.y * 128;
  const size_t nBase = (size_t)blockIdx.x * 128;

  const int srow = t >> 2;
  const int scol = (t & 3) * 8;
  const bf16* gA = A + (mBase + srow) * K + scol;
  const bf16* gB = BT + (nBase + srow) * K + scol;
  bf16* lA = ldsA + wid * 512;
  bf16* lB = ldsB + wid * 512;

  f32x4 acc[4][4];
#pragma unroll
  for (int i = 0; i < 4; ++i)
#pragma unroll
    for (int j = 0; j < 4; ++j) acc[i][j] = (f32x4){0.f, 0.f, 0.f, 0.f};

  for (int k0 = 0; k0 < K; k0 += 32) {
    gload_lds16(gA + k0, lA);
    gload_lds16(gA + 64 * K + k0, lA + 2048);
    gload_lds16(gB + k0, lB);
    gload_lds16(gB + 64 * K + k0, lB + 2048);
    asm volatile("s_waitcnt vmcnt(0)" ::: "memory");
    __syncthreads();

    bf16x8 aF[4], bF[4];
#pragma unroll
    for (int i = 0; i < 4; ++i)
      aF[i] = *(const bf16x8*)&ldsA[(wr * 64 + i * 16 + fr) * 32 + fko];
#pragma unroll
    for (int j = 0; j < 4; ++j)
      bF[j] = *(const bf16x8*)&ldsB[(wc * 64 + j * 16 + fr) * 32 + fko];
#pragma unroll
    for (int i = 0; i < 4; ++i)
#pragma unroll
      for (int j = 0; j < 4; ++j)
        acc[i][j] = __builtin_amdgcn_mfma_f32_16x16x32_bf16(aF[i], bF[j], acc[i][j], 0, 0, 0);
    __syncthreads();
  }

  const int orow = (int)mBase + wr * 64 + (lane >> 4) * 4;
  const int ocol = (int)nBase + wc * 64 + fr;
#pragma unroll
  for (int j = 0; j < 4; ++j) {
    const float bj = bias[ocol + j * 16];
#pragma unroll
    for (int i = 0; i < 4; ++i)
#pragma unroll
      for (int r = 0; r < 4; ++r) {
        float v = fmaxf(acc[i][j][r] + bj, 0.f);
        size_t idx = (size_t)(orow + i * 16 + r) * N + (ocol + j * 16);
        if constexpr (sizeof(OutT) == 2) out[idx] = __float2bfloat16(v);
        else out[idx] = v;
      }
  }
}

struct QKVArgs {
  const bf16* A[3];
  const bf16* BT[3];
  const float* bias[3];
  bf16* out[3];
};

__global__ __launch_bounds__(256) void gemm_qkv_kernel(QKVArgs args) {
  const int z = blockIdx.z;
  gemm128_core<bf16>(args.A[z], args.BT[z], args.bias[z], args.out[z]);
}

__global__ __launch_bounds__(256) void gemm_out_kernel(const bf16* __restrict__ A,
                                                       const bf16* __restrict__ BT,
                                                       const float* __restrict__ bias,
                                                       float* __restrict__ out) {
  gemm128_core<float>(A, BT, bias, out);
}

// ---------------------------------------------------------------- flash attention (causal, swapped QK^T, PAIRED)
// Block handles q-tiles {p, 31-p} sequentially -> uniform 33 KV tiles/block.
// Grid: 512 blocks (16 pairs x 32 bh) = exactly 2 blocks/CU, zero drain tail.
__global__ __launch_bounds__(256, 4) void attn_kernel(const bf16* __restrict__ Qb,
                                                      const bf16* __restrict__ Kb,
                                                      const bf16* __restrict__ VTb,
                                                      bf16* __restrict__ Ob) {
  constexpr int Dm = 1024, S = 2048;
  __shared__ bf16 ldsKV[16384];   // [K buf0|K buf1|V buf0|V buf1] 4096 each (32KB)
  const int t = threadIdx.x, l = t & 63, wid = t >> 6;

  // XCD chunk swizzle (bijective, 512 = 8*64): each XCD gets 4 bh x 16 pairs
  const int lin = blockIdx.y * 16 + blockIdx.x;
  const int swz = (lin & 7) * 64 + (lin >> 3);
  const int bh = swz >> 4, pairp = swz & 15;
  const int b = bh >> 4, h = bh & 15;
  const int q4 = l & 15, fg = l >> 4;              // lane's q-col, k-group
  const bf16* Qg = Qb + (size_t)b * S * Dm + h * 64;
  const bf16* Kg = Kb + (size_t)b * S * Dm + h * 64;
  const bf16* VTg = VTb + (size_t)bh * 64 * S;

  // staging: lane covers (row = base + l>>3 (+8), chunk = (l&7) ^ (row&7))
  const int srow = l >> 3;
  const int schunk = (l & 7) ^ srow;
  const bf16* kSrc = Kg + (size_t)(wid * 16 + srow) * Dm + schunk * 8;
  const bf16* vSrc = VTg + (size_t)(wid * 16 + srow) * S + schunk * 8;
  bf16* kDst = ldsKV + wid * 1024;                 // + buf*4096
  bf16* vDst = ldsKV + 8192 + wid * 1024;

  // bpermute indices for P^T B-frag build
  const int idx0 = ((q4 + ((l & 16) ? 32 : 0)) << 2);
  const int idx1 = idx0 + 64;

#pragma unroll 1
  for (int ph = 0; ph < 2; ++ph) {
    const int qt = ph ? (31 - pairp) : pairp;
    const int qb = qt * 64;
    const int qw = qb + wid * 16;                  // this wave's 16 q-rows

    // Q fragments (B-operand: col=q4, k-elems fg*8.. of d-slice kd*32)
    bf16x8 qF[2];
#pragma unroll
    for (int kd = 0; kd < 2; ++kd)
      qF[kd] = *(const bf16x8*)&Qg[(size_t)(qw + q4) * Dm + kd * 32 + fg * 8];

    f32x4 oacc[4];                                 // O^T: [d-block][q] accum
#pragma unroll
    for (int n = 0; n < 4; ++n) oacc[n] = (f32x4){0.f, 0.f, 0.f, 0.f};
    float mrow = -3.0e38f, lsum = 0.f;             // per-lane scalars (one q-row)

    const int nTiles = qt + 1;

    // prologue: stage tile 0 into buf 0
    gload_lds16(kSrc, kDst);
    gload_lds16(kSrc + 8 * Dm, kDst + 512);
    gload_lds16(vSrc, vDst);
    gload_lds16(vSrc + 8 * S, vDst + 512);
    __syncthreads();

    int buf = 0;
    for (int tile = 0; tile < nTiles; ++tile) {
      const int kvb = tile * 64;
      if (tile + 1 < nTiles) {                     // prefetch next tile
        const int nb = kvb + 64;
        gload_lds16(kSrc + (size_t)nb * Dm, kDst + (buf ^ 1) * 4096);
        gload_lds16(kSrc + (size_t)(nb + 8) * Dm, kDst + (buf ^ 1) * 4096 + 512);
        gload_lds16(vSrc + nb, vDst + (buf ^ 1) * 4096);
        gload_lds16(vSrc + nb + 8 * S, vDst + (buf ^ 1) * 4096 + 512);
      }
      const bf16* kb = ldsKV + buf * 4096;
      const bf16* vb = ldsKV + 8192 + buf * 4096;

      // S^T = K Q^T : D[kv][q], col = q4
      f32x4 sT[4];
#pragma unroll
      for (int n = 0; n < 4; ++n) sT[n] = (f32x4){0.f, 0.f, 0.f, 0.f};
      __builtin_amdgcn_s_setprio(1);
#pragma unroll
      for (int n = 0; n < 4; ++n) {
#pragma unroll
        for (int kd = 0; kd < 2; ++kd) {
          bf16x8 kf = *(const bf16x8*)&kb[(n * 16 + q4) * 64 + (((kd * 4 + fg) ^ (q4 & 7)) * 8)];
          sT[n] = __builtin_amdgcn_mfma_f32_16x16x32_bf16(kf, qF[kd], sT[n], 0, 0, 0);
        }
      }
      __builtin_amdgcn_s_setprio(0);
      // scale + causal mask (only diagonal tile masks)
      const bool needmask = (tile == nTiles - 1);
      const int qrow = qw + q4;
#pragma unroll
      for (int n = 0; n < 4; ++n)
#pragma unroll
        for (int r = 0; r < 4; ++r) {
          float vv = sT[n][r] * 0.125f;            // 1/sqrt(64)
          if (needmask) {
            int kv = kvb + n * 16 + fg * 4 + r;
            if (kv > qrow) vv = -1e30f;
          }
          sT[n][r] = vv;
        }
      // online softmax: in-lane tree over 16 + 2 shfl_xor across k-groups
      float tmax = -3.0e38f;
#pragma unroll
      for (int n = 0; n < 4; ++n)
        tmax = fmaxf(tmax, fmaxf(fmaxf(sT[n][0], sT[n][1]), fmaxf(sT[n][2], sT[n][3])));
      tmax = fmaxf(tmax, __shfl_xor(tmax, 16, 64));
      tmax = fmaxf(tmax, __shfl_xor(tmax, 32, 64));
      const float mnew = fmaxf(mrow, tmax);
      const float corr = __expf(mrow - mnew);
      mrow = mnew;
      float rs = 0.f;
#pragma unroll
      for (int n = 0; n < 4; ++n)
#pragma unroll
        for (int r = 0; r < 4; ++r) {
          float p = __expf(sT[n][r] - mnew);
          sT[n][r] = p;
          rs += p;
        }
      rs += __shfl_xor(rs, 16, 64);
      rs += __shfl_xor(rs, 32, 64);
      lsum = lsum * corr + rs;
#pragma unroll
      for (int n = 0; n < 4; ++n)
#pragma unroll
        for (int r = 0; r < 4; ++r) oacc[n][r] *= corr;

      // PV: O^T += V^T P^T. Build P^T B-frags in-register.
#pragma unroll
      for (int ks = 0; ks < 2; ++ks) {
        const unsigned X0 = pk2(sT[2 * ks][0], sT[2 * ks][1]);
        const unsigned X1 = pk2(sT[2 * ks][2], sT[2 * ks][3]);
        const unsigned Y0 = pk2(sT[2 * ks + 1][0], sT[2 * ks + 1][1]);
        const unsigned Y1 = pk2(sT[2 * ks + 1][2], sT[2 * ks + 1][3]);
        union { int u[4]; bf16x8 v; } bfr;
        {
          int zx = __builtin_amdgcn_ds_bpermute(idx0, (int)X0);
          int zy = __builtin_amdgcn_ds_bpermute(idx0, (int)Y0);
          bfr.u[0] = (l & 32) ? zy : zx;
          zx = __builtin_amdgcn_ds_bpermute(idx0, (int)X1);
          zy = __builtin_amdgcn_ds_bpermute(idx0, (int)Y1);
          bfr.u[1] = (l & 32) ? zy : zx;
          zx = __builtin_amdgcn_ds_bpermute(idx1, (int)X0);
          zy = __builtin_amdgcn_ds_bpermute(idx1, (int)Y0);
          bfr.u[2] = (l & 32) ? zy : zx;
          zx = __builtin_amdgcn_ds_bpermute(idx1, (int)X1);
          zy = __builtin_amdgcn_ds_bpermute(idx1, (int)Y1);
          bfr.u[3] = (l & 32) ? zy : zx;
        }
        __builtin_amdgcn_s_setprio(1);
#pragma unroll
        for (int dblk = 0; dblk < 4; ++dblk) {
          bf16x8 vf = *(const bf16x8*)&vb[(dblk * 16 + q4) * 64 + (((ks * 4 + fg) ^ (q4 & 7)) * 8)];
          oacc[dblk] = __builtin_amdgcn_mfma_f32_16x16x32_bf16(vf, bfr.v, oacc[dblk], 0, 0, 0);
        }
        __builtin_amdgcn_s_setprio(0);
      }
      __syncthreads();   // drains prefetch (vmcnt0) + guards buf overwrite
      buf ^= 1;
    }

    // epilogue: per-wave LDS transpose of O^T -> coalesced store
    bf16* ldsT = ldsKV + wid * 1152;               // 16 rows x 72 (pad) bf16
    const float inv = 1.f / lsum;
#pragma unroll
    for (int dblk = 0; dblk < 4; ++dblk)
#pragma unroll
      for (int r = 0; r < 4; ++r) {
        int d = dblk * 16 + fg * 4 + r;
        ldsT[q4 * 72 + d] = __float2bfloat16(oacc[dblk][r] * inv);
      }
    asm volatile("s_waitcnt lgkmcnt(0)" ::: "memory");
    __builtin_amdgcn_sched_barrier(0);
    const int rq = l >> 2, dq = (l & 3) * 16;
#pragma unroll
    for (int i = 0; i < 2; ++i) {
      uint4 w = *(const uint4*)&ldsT[rq * 72 + dq + 8 * i];
      *(uint4*)&Ob[((size_t)b * S + qw + rq) * Dm + h * 64 + dq + 8 * i] = w;
    }
    __syncthreads();   // all epilogue LDS reads done before next phase's staging
  }
}

// ---------------------------------------------------------------- launch
extern "C" void kernel_launch(void* const* d_in, const int* in_sizes, int n_in,
                              void* d_out, int out_size, void* d_ws, size_t ws_size,
                              hipStream_t stream) {
  const float* query = (const float*)d_in[0];
  const float* key   = (const float*)d_in[1];
  const float* value = (const float*)d_in[2];
  const float* Wq = (const float*)d_in[3]; const float* bq = (const float*)d_in[4];
  const float* Wk = (const float*)d_in[5]; const float* bk = (const float*)d_in[6];
  const float* Wv = (const float*)d_in[7]; const float* bv = (const float*)d_in[8];
  const float* Wo = (const float*)d_in[9]; const float* bo = (const float*)d_in[10];
  float* out = (float*)d_out;

  char* ws = (char*)d_ws;
  const size_t MB = 1024 * 1024;
  bf16* xq  = (bf16*)(ws + 0 * MB);
  bf16* xk  = (bf16*)(ws + 8 * MB);
  bf16* xv  = (bf16*)(ws + 16 * MB);
  bf16* qp  = (bf16*)(ws + 24 * MB);
  bf16* kp  = (bf16*)(ws + 32 * MB);
  bf16* vp  = (bf16*)(ws + 40 * MB);
  bf16* WqT = (bf16*)(ws + 48 * MB);
  bf16* WkT = (bf16*)(ws + 50 * MB);
  bf16* WvT = (bf16*)(ws + 52 * MB);
  bf16* WoT = (bf16*)(ws + 54 * MB);
  bf16* VT   = xq;   // xq consumed by gemm_qkv before vtrans runs
  bf16* attn = xk;   // xk consumed by gemm_qkv before attn runs

  PrepArgs pa;
  pa.x[0] = query; pa.x[1] = key; pa.x[2] = value;
  pa.y[0] = xq; pa.y[1] = xk; pa.y[2] = xv;
  pa.W[0] = Wq; pa.W[1] = Wk; pa.W[2] = Wv; pa.W[3] = Wo;
  pa.WT[0] = WqT; pa.WT[1] = WkT; pa.WT[2] = WvT; pa.WT[3] = WoT;
  prep_kernel<<<10240, 256, 0, stream>>>(pa);

  QKVArgs qa;
  qa.A[0] = xq;  qa.A[1] = xk;  qa.A[2] = xv;
  qa.BT[0] = WqT; qa.BT[1] = WkT; qa.BT[2] = WvT;
  qa.bias[0] = bq; qa.bias[1] = bk; qa.bias[2] = bv;
  qa.out[0] = qp; qa.out[1] = kp; qa.out[2] = vp;
  gemm_qkv_kernel<<<dim3(8, 32, 3), 256, 0, stream>>>(qa);

  vtrans_kernel<<<dim3(32, 32), 256, 0, stream>>>(vp, VT);
  attn_kernel<<<dim3(16, 32), 256, 0, stream>>>(qp, kp, VT, attn);
  gemm_out_kernel<<<dim3(8, 32), 256, 0, stream>>>(attn, WoT, bo, out);
}

// Round 6
// 233.650 us; speedup vs baseline: 1.5266x; 1.0227x over previous
//
#include <hip/hip_runtime.h>
#include <hip/hip_bf16.h>

using bf16 = __hip_bfloat16;
typedef __attribute__((ext_vector_type(8))) short bf16x8;   // 8 bf16 = 4 VGPRs (MFMA A/B frag)
typedef __attribute__((ext_vector_type(4))) float f32x4;    // MFMA C/D frag

#define DEV __device__ __forceinline__

DEV void gload_lds16(const void* g, void* l) {
  __builtin_amdgcn_global_load_lds((const __attribute__((address_space(1))) void*)g,
                                   (__attribute__((address_space(3))) void*)l, 16, 0, 0);
}

DEV unsigned pk2(float lo, float hi) {   // pack 2 f32 -> 2 bf16
  union { bf16 h[2]; unsigned u; } z;
  z.h[0] = __float2bfloat16(lo);
  z.h[1] = __float2bfloat16(hi);
  return z.u;
}

// ---------------------------------------------------------------- prep: 3x cvt + 4x wtrans fused
struct PrepArgs {
  const float* x[3]; bf16* y[3];
  const float* W[4]; bf16* WT[4];
};

__global__ __launch_bounds__(256) void prep_kernel(PrepArgs a) {
  __shared__ float tile[32][33];
  const int b = blockIdx.x;
  if (b < 6144) {
    const int which = b >> 11, blk = b & 2047;
    const int i = blk * 256 + threadIdx.x;
    const float4* xv = (const float4*)a.x[which];
    float4 p = xv[i * 2];
    float4 q = xv[i * 2 + 1];
    union { bf16 h[8]; uint4 v; } u;
    u.h[0] = __float2bfloat16(p.x); u.h[1] = __float2bfloat16(p.y);
    u.h[2] = __float2bfloat16(p.z); u.h[3] = __float2bfloat16(p.w);
    u.h[4] = __float2bfloat16(q.x); u.h[5] = __float2bfloat16(q.y);
    u.h[6] = __float2bfloat16(q.z); u.h[7] = __float2bfloat16(q.w);
    *(uint4*)&a.y[which][(size_t)i * 8] = u.v;
  } else {
    const int w = (b - 6144) >> 10, blk = (b - 6144) & 1023;
    const float* W = a.W[w];
    bf16* WT = a.WT[w];
    const int tx = threadIdx.x & 31, ty = threadIdx.x >> 5;
    const int n0 = (blk & 31) * 32, k0 = (blk >> 5) * 32;
#pragma unroll
    for (int i = ty; i < 32; i += 8)
      tile[i][tx] = W[(size_t)(k0 + i) * 1024 + n0 + tx];
    __syncthreads();
#pragma unroll
    for (int i = ty; i < 32; i += 8)
      WT[(size_t)(n0 + i) * 1024 + k0 + tx] = __float2bfloat16(tile[tx][i]);
  }
}

// v (projected, bf16 [4096][1024]) -> VT [bh=32][dh=64][S=2048]
__global__ __launch_bounds__(256) void vtrans_kernel(const bf16* __restrict__ v,
                                                     bf16* __restrict__ VT) {
  __shared__ bf16 tile[64 * 64];
  const int t = threadIdx.x;
  const int bh = blockIdx.y, b = bh >> 4, h = bh & 15;
  const int s0 = blockIdx.x * 64;
  const int r0 = t >> 3, c8 = t & 7;
#pragma unroll
  for (int it = 0; it < 2; ++it) {
    int r = it * 32 + r0;
    uint4 d = *(const uint4*)&v[(size_t)(b * 2048 + s0 + r) * 1024 + h * 64 + c8 * 8];
    *(uint4*)&tile[r * 64 + ((c8 ^ (r >> 3)) * 8)] = d;
  }
  __syncthreads();
#pragma unroll
  for (int it = 0; it < 2; ++it) {
    int d = it * 32 + r0;
    int sc = c8 * 8;
    union { bf16 h[8]; uint4 v4; } u;
#pragma unroll
    for (int j = 0; j < 8; ++j) {
      int row = sc + j;
      u.h[j] = tile[row * 64 + (((d >> 3) ^ (row >> 3)) * 8) + (d & 7)];
    }
    *(uint4*)&VT[((size_t)bh * 64 + d) * 2048 + s0 + sc] = u.v4;
  }
}

// ---------------------------------------------------------------- GEMM 128x128, BK=32, 2-phase dbuf
// A [M][1024] bf16 row-major, BT [N][1024] bf16, bias f32[N]; out = relu(A@B+bias)
template <typename OutT>
DEV void gemm128_core(const bf16* __restrict__ A, const bf16* __restrict__ BT,
                      const float* __restrict__ bias, OutT* __restrict__ out) {
  constexpr int K = 1024, N = 1024;
  __shared__ bf16 ldsA[2][128 * 32];    // 8KB per buf
  __shared__ bf16 ldsB[2][128 * 32];
  const int t = threadIdx.x;
  const int lane = t & 63, wid = t >> 6;
  const int wr = wid >> 1, wc = wid & 1;
  const int fr = lane & 15, fko = (lane >> 4) * 8;
  const size_t mBase = (size_t)blockIdx.y * 128;
  const size_t nBase = (size_t)blockIdx.x * 128;

  const int srow = t >> 2;              // 0..63
  const int scol = (t & 3) * 8;         // 0/8/16/24
  const bf16* gA = A + (mBase + srow) * K + scol;
  const bf16* gB = BT + (nBase + srow) * K + scol;
  const int ldst = wid * 512;           // wave-uniform LDS dest offset (HW adds lane*16B)

  f32x4 acc[4][4];
#pragma unroll
  for (int i = 0; i < 4; ++i)
#pragma unroll
    for (int j = 0; j < 4; ++j) acc[i][j] = (f32x4){0.f, 0.f, 0.f, 0.f};

  // prologue: stage K-step 0 into buf 0
  gload_lds16(gA, &ldsA[0][ldst]);
  gload_lds16(gA + 64 * K, &ldsA[0][ldst + 2048]);
  gload_lds16(gB, &ldsB[0][ldst]);
  gload_lds16(gB + 64 * K, &ldsB[0][ldst + 2048]);
  __syncthreads();   // compiler drains vmcnt(0) before barrier

  int buf = 0;
  for (int k0 = 0; k0 < K; k0 += 32) {
    // issue next K-step's staging first — loads fly during this step's compute
    if (k0 + 32 < K) {
      const int kn = k0 + 32;
      gload_lds16(gA + kn, &ldsA[buf ^ 1][ldst]);
      gload_lds16(gA + 64 * K + kn, &ldsA[buf ^ 1][ldst + 2048]);
      gload_lds16(gB + kn, &ldsB[buf ^ 1][ldst]);
      gload_lds16(gB + 64 * K + kn, &ldsB[buf ^ 1][ldst + 2048]);
    }
    bf16x8 aF[4], bF[4];
#pragma unroll
    for (int i = 0; i < 4; ++i)
      aF[i] = *(const bf16x8*)&ldsA[buf][(wr * 64 + i * 16 + fr) * 32 + fko];
#pragma unroll
    for (int j = 0; j < 4; ++j)
      bF[j] = *(const bf16x8*)&ldsB[buf][(wc * 64 + j * 16 + fr) * 32 + fko];
#pragma unroll
    for (int i = 0; i < 4; ++i)
#pragma unroll
      for (int j = 0; j < 4; ++j)
        acc[i][j] = __builtin_amdgcn_mfma_f32_16x16x32_bf16(aF[i], bF[j], acc[i][j], 0, 0, 0);
    __syncthreads();   // vmcnt(0) drain lands the prefetch; guards buf reuse
    buf ^= 1;
  }

  const int orow = (int)mBase + wr * 64 + (lane >> 4) * 4;
  const int ocol = (int)nBase + wc * 64 + fr;
#pragma unroll
  for (int j = 0; j < 4; ++j) {
    const float bj = bias[ocol + j * 16];
#pragma unroll
    for (int i = 0; i < 4; ++i)
#pragma unroll
      for (int r = 0; r < 4; ++r) {
        float v = fmaxf(acc[i][j][r] + bj, 0.f);
        size_t idx = (size_t)(orow + i * 16 + r) * N + (ocol + j * 16);
        if constexpr (sizeof(OutT) == 2) out[idx] = __float2bfloat16(v);
        else out[idx] = v;
      }
  }
}

struct QKVArgs {
  const bf16* A[3];
  const bf16* BT[3];
  const float* bias[3];
  bf16* out[3];
};

__global__ __launch_bounds__(256) void gemm_qkv_kernel(QKVArgs args) {
  const int z = blockIdx.z;
  gemm128_core<bf16>(args.A[z], args.BT[z], args.bias[z], args.out[z]);
}

__global__ __launch_bounds__(256) void gemm_out_kernel(const bf16* __restrict__ A,
                                                       const bf16* __restrict__ BT,
                                                       const float* __restrict__ bias,
                                                       float* __restrict__ out) {
  gemm128_core<float>(A, BT, bias, out);
}

// ---------------------------------------------------------------- flash attention (causal, swapped QK^T, PAIRED)
// Block handles q-tiles {p, 31-p} sequentially -> uniform 33 KV tiles/block.
// Grid: 512 blocks (16 pairs x 32 bh) = exactly 2 blocks/CU, zero drain tail.
__global__ __launch_bounds__(256, 4) void attn_kernel(const bf16* __restrict__ Qb,
                                                      const bf16* __restrict__ Kb,
                                                      const bf16* __restrict__ VTb,
                                                      bf16* __restrict__ Ob) {
  constexpr int Dm = 1024, S = 2048;
  __shared__ bf16 ldsKV[16384];   // [K buf0|K buf1|V buf0|V buf1] 4096 each (32KB)
  const int t = threadIdx.x, l = t & 63, wid = t >> 6;

  // XCD chunk swizzle (bijective, 512 = 8*64): each XCD gets 4 bh x 16 pairs
  const int lin = blockIdx.y * 16 + blockIdx.x;
  const int swz = (lin & 7) * 64 + (lin >> 3);
  const int bh = swz >> 4, pairp = swz & 15;
  const int b = bh >> 4, h = bh & 15;
  const int q4 = l & 15, fg = l >> 4;              // lane's q-col, k-group
  const bf16* Qg = Qb + (size_t)b * S * Dm + h * 64;
  const bf16* Kg = Kb + (size_t)b * S * Dm + h * 64;
  const bf16* VTg = VTb + (size_t)bh * 64 * S;

  // staging: lane covers (row = base + l>>3 (+8), chunk = (l&7) ^ (row&7))
  const int srow = l >> 3;
  const int schunk = (l & 7) ^ srow;
  const bf16* kSrc = Kg + (size_t)(wid * 16 + srow) * Dm + schunk * 8;
  const bf16* vSrc = VTg + (size_t)(wid * 16 + srow) * S + schunk * 8;
  bf16* kDst = ldsKV + wid * 1024;                 // + buf*4096
  bf16* vDst = ldsKV + 8192 + wid * 1024;

  // bpermute indices for P^T B-frag build
  const int idx0 = ((q4 + ((l & 16) ? 32 : 0)) << 2);
  const int idx1 = idx0 + 64;

#pragma unroll 1
  for (int ph = 0; ph < 2; ++ph) {
    const int qt = ph ? (31 - pairp) : pairp;
    const int qb = qt * 64;
    const int qw = qb + wid * 16;                  // this wave's 16 q-rows

    // Q fragments (B-operand: col=q4, k-elems fg*8.. of d-slice kd*32)
    bf16x8 qF[2];
#pragma unroll
    for (int kd = 0; kd < 2; ++kd)
      qF[kd] = *(const bf16x8*)&Qg[(size_t)(qw + q4) * Dm + kd * 32 + fg * 8];

    f32x4 oacc[4];                                 // O^T: [d-block][q] accum
#pragma unroll
    for (int n = 0; n < 4; ++n) oacc[n] = (f32x4){0.f, 0.f, 0.f, 0.f};
    float mrow = -3.0e38f, lsum = 0.f;             // per-lane scalars (one q-row)

    const int nTiles = qt + 1;

    // prologue: stage tile 0 into buf 0
    gload_lds16(kSrc, kDst);
    gload_lds16(kSrc + 8 * Dm, kDst + 512);
    gload_lds16(vSrc, vDst);
    gload_lds16(vSrc + 8 * S, vDst + 512);
    __syncthreads();

    int buf = 0;
    for (int tile = 0; tile < nTiles; ++tile) {
      const int kvb = tile * 64;
      if (tile + 1 < nTiles) {                     // prefetch next tile
        const int nb = kvb + 64;
        gload_lds16(kSrc + (size_t)nb * Dm, kDst + (buf ^ 1) * 4096);
        gload_lds16(kSrc + (size_t)(nb + 8) * Dm, kDst + (buf ^ 1) * 4096 + 512);
        gload_lds16(vSrc + nb, vDst + (buf ^ 1) * 4096);
        gload_lds16(vSrc + nb + 8 * S, vDst + (buf ^ 1) * 4096 + 512);
      }
      const bf16* kb = ldsKV + buf * 4096;
      const bf16* vb = ldsKV + 8192 + buf * 4096;

      // S^T = K Q^T : D[kv][q], col = q4
      f32x4 sT[4];
#pragma unroll
      for (int n = 0; n < 4; ++n) sT[n] = (f32x4){0.f, 0.f, 0.f, 0.f};
      __builtin_amdgcn_s_setprio(1);
#pragma unroll
      for (int n = 0; n < 4; ++n) {
#pragma unroll
        for (int kd = 0; kd < 2; ++kd) {
          bf16x8 kf = *(const bf16x8*)&kb[(n * 16 + q4) * 64 + (((kd * 4 + fg) ^ (q4 & 7)) * 8)];
          sT[n] = __builtin_amdgcn_mfma_f32_16x16x32_bf16(kf, qF[kd], sT[n], 0, 0, 0);
        }
      }
      __builtin_amdgcn_s_setprio(0);
      // scale + causal mask (only diagonal tile masks)
      const bool needmask = (tile == nTiles - 1);
      const int qrow = qw + q4;
#pragma unroll
      for (int n = 0; n < 4; ++n)
#pragma unroll
        for (int r = 0; r < 4; ++r) {
          float vv = sT[n][r] * 0.125f;            // 1/sqrt(64)
          if (needmask) {
            int kv = kvb + n * 16 + fg * 4 + r;
            if (kv > qrow) vv = -1e30f;
          }
          sT[n][r] = vv;
        }
      // online softmax: in-lane tree over 16 + 2 shfl_xor across k-groups
      float tmax = -3.0e38f;
#pragma unroll
      for (int n = 0; n < 4; ++n)
        tmax = fmaxf(tmax, fmaxf(fmaxf(sT[n][0], sT[n][1]), fmaxf(sT[n][2], sT[n][3])));
      tmax = fmaxf(tmax, __shfl_xor(tmax, 16, 64));
      tmax = fmaxf(tmax, __shfl_xor(tmax, 32, 64));
      const float mnew = fmaxf(mrow, tmax);
      const float corr = __expf(mrow - mnew);
      mrow = mnew;
      float rs = 0.f;
#pragma unroll
      for (int n = 0; n < 4; ++n)
#pragma unroll
        for (int r = 0; r < 4; ++r) {
          float p = __expf(sT[n][r] - mnew);
          sT[n][r] = p;
          rs += p;
        }
      rs += __shfl_xor(rs, 16, 64);
      rs += __shfl_xor(rs, 32, 64);
      lsum = lsum * corr + rs;
#pragma unroll
      for (int n = 0; n < 4; ++n)
#pragma unroll
        for (int r = 0; r < 4; ++r) oacc[n][r] *= corr;

      // PV: O^T += V^T P^T. Build P^T B-frags in-register.
#pragma unroll
      for (int ks = 0; ks < 2; ++ks) {
        const unsigned X0 = pk2(sT[2 * ks][0], sT[2 * ks][1]);
        const unsigned X1 = pk2(sT[2 * ks][2], sT[2 * ks][3]);
        const unsigned Y0 = pk2(sT[2 * ks + 1][0], sT[2 * ks + 1][1]);
        const unsigned Y1 = pk2(sT[2 * ks + 1][2], sT[2 * ks + 1][3]);
        union { int u[4]; bf16x8 v; } bfr;
        {
          int zx = __builtin_amdgcn_ds_bpermute(idx0, (int)X0);
          int zy = __builtin_amdgcn_ds_bpermute(idx0, (int)Y0);
          bfr.u[0] = (l & 32) ? zy : zx;
          zx = __builtin_amdgcn_ds_bpermute(idx0, (int)X1);
          zy = __builtin_amdgcn_ds_bpermute(idx0, (int)Y1);
          bfr.u[1] = (l & 32) ? zy : zx;
          zx = __builtin_amdgcn_ds_bpermute(idx1, (int)X0);
          zy = __builtin_amdgcn_ds_bpermute(idx1, (int)Y0);
          bfr.u[2] = (l & 32) ? zy : zx;
          zx = __builtin_amdgcn_ds_bpermute(idx1, (int)X1);
          zy = __builtin_amdgcn_ds_bpermute(idx1, (int)Y1);
          bfr.u[3] = (l & 32) ? zy : zx;
        }
        __builtin_amdgcn_s_setprio(1);
#pragma unroll
        for (int dblk = 0; dblk < 4; ++dblk) {
          bf16x8 vf = *(const bf16x8*)&vb[(dblk * 16 + q4) * 64 + (((ks * 4 + fg) ^ (q4 & 7)) * 8)];
          oacc[dblk] = __builtin_amdgcn_mfma_f32_16x16x32_bf16(vf, bfr.v, oacc[dblk], 0, 0, 0);
        }
        __builtin_amdgcn_s_setprio(0);
      }
      __syncthreads();   // drains prefetch (vmcnt0) + guards buf overwrite
      buf ^= 1;
    }

    // epilogue: per-wave LDS transpose of O^T -> coalesced store
    bf16* ldsT = ldsKV + wid * 1152;               // 16 rows x 72 (pad) bf16
    const float inv = 1.f / lsum;
#pragma unroll
    for (int dblk = 0; dblk < 4; ++dblk)
#pragma unroll
      for (int r = 0; r < 4; ++r) {
        int d = dblk * 16 + fg * 4 + r;
        ldsT[q4 * 72 + d] = __float2bfloat16(oacc[dblk][r] * inv);
      }
    asm volatile("s_waitcnt lgkmcnt(0)" ::: "memory");
    __builtin_amdgcn_sched_barrier(0);
    const int rq = l >> 2, dq = (l & 3) * 16;
#pragma unroll
    for (int i = 0; i < 2; ++i) {
      uint4 w = *(const uint4*)&ldsT[rq * 72 + dq + 8 * i];
      *(uint4*)&Ob[((size_t)b * S + qw + rq) * Dm + h * 64 + dq + 8 * i] = w;
    }
    __syncthreads();   // all epilogue LDS reads done before next phase's staging
  }
}

// ---------------------------------------------------------------- launch
extern "C" void kernel_launch(void* const* d_in, const int* in_sizes, int n_in,
                              void* d_out, int out_size, void* d_ws, size_t ws_size,
                              hipStream_t stream) {
  const float* query = (const float*)d_in[0];
  const float* key   = (const float*)d_in[1];
  const float* value = (const float*)d_in[2];
  const float* Wq = (const float*)d_in[3]; const float* bq = (const float*)d_in[4];
  const float* Wk = (const float*)d_in[5]; const float* bk = (const float*)d_in[6];
  const float* Wv = (const float*)d_in[7]; const float* bv = (const float*)d_in[8];
  const float* Wo = (const float*)d_in[9]; const float* bo = (const float*)d_in[10];
  float* out = (float*)d_out;

  char* ws = (char*)d_ws;
  const size_t MB = 1024 * 1024;
  bf16* xq  = (bf16*)(ws + 0 * MB);
  bf16* xk  = (bf16*)(ws + 8 * MB);
  bf16* xv  = (bf16*)(ws + 16 * MB);
  bf16* qp  = (bf16*)(ws + 24 * MB);
  bf16* kp  = (bf16*)(ws + 32 * MB);
  bf16* vp  = (bf16*)(ws + 40 * MB);
  bf16* WqT = (bf16*)(ws + 48 * MB);
  bf16* WkT = (bf16*)(ws + 50 * MB);
  bf16* WvT = (bf16*)(ws + 52 * MB);
  bf16* WoT = (bf16*)(ws + 54 * MB);
  bf16* VT   = xq;   // xq consumed by gemm_qkv before vtrans runs
  bf16* attn = xk;   // xk consumed by gemm_qkv before attn runs

  PrepArgs pa;
  pa.x[0] = query; pa.x[1] = key; pa.x[2] = value;
  pa.y[0] = xq; pa.y[1] = xk; pa.y[2] = xv;
  pa.W[0] = Wq; pa.W[1] = Wk; pa.W[2] = Wv; pa.W[3] = Wo;
  pa.WT[0] = WqT; pa.WT[1] = WkT; pa.WT[2] = WvT; pa.WT[3] = WoT;
  prep_kernel<<<10240, 256, 0, stream>>>(pa);

  QKVArgs qa;
  qa.A[0] = xq;  qa.A[1] = xk;  qa.A[2] = xv;
  qa.BT[0] = WqT; qa.BT[1] = WkT; qa.BT[2] = WvT;
  qa.bias[0] = bq; qa.bias[1] = bk; qa.bias[2] = bv;
  qa.out[0] = qp; qa.out[1] = kp; qa.out[2] = vp;
  gemm_qkv_kernel<<<dim3(8, 32, 3), 256, 0, stream>>>(qa);

  vtrans_kernel<<<dim3(32, 32), 256, 0, stream>>>(vp, VT);
  attn_kernel<<<dim3(16, 32), 256, 0, stream>>>(qp, kp, VT, attn);
  gemm_out_kernel<<<dim3(8, 32), 256, 0, stream>>>(attn, WoT, bo, out);
}